// Round 6
// baseline (84.415 us; speedup 1.0000x reference)
//
#include <hip/hip_runtime.h>
#include <hip/hip_bf16.h>
#include <stdint.h>

#define HID 768

typedef short bf16x8 __attribute__((ext_vector_type(8)));
typedef unsigned short ushort8_t __attribute__((ext_vector_type(8)));
typedef float f32x4 __attribute__((ext_vector_type(4)));

// packed f32x2 -> bf16x2 (compiler emits v_cvt_pk_bf16_f32)
__device__ __forceinline__ unsigned int pack2bf(float x, float y) {
    __hip_bfloat162 h = __float22bfloat162_rn(make_float2(x, y));
    return *reinterpret_cast<unsigned int*>(&h);
}
__device__ __forceinline__ unsigned short f2bf1(float x) {
    __hip_bfloat16 h = __float2bfloat16(x);
    return *reinterpret_cast<unsigned short*>(&h);
}

// async global->LDS, 16B per lane; lds dest = wave-uniform base + lane*16
__device__ __forceinline__ void gload_lds16(const void* g, void* l) {
    __builtin_amdgcn_global_load_lds(
        (const __attribute__((address_space(1))) unsigned int*)g,
        (__attribute__((address_space(3))) unsigned int*)l, 16, 0, 0);
}

// ---------------- merged transpose+cast: 4 regions, f32 [R][C] -> bf16 [C][R] ----
__global__ void prep_k(const float* __restrict__ W1,
                       const float* __restrict__ W2,
                       const float* __restrict__ W3,
                       unsigned short* __restrict__ W1x,
                       unsigned short* __restrict__ W2t,
                       unsigned short* __restrict__ W3t) {
    __shared__ float t[32][33];
    int b = blockIdx.x;
    const float* in; unsigned short* op; int R, C, bx, by;
    if (b < 576)       { in = W1;           op = W1x;           R = 768; C = 768; bx = b % 24;        by = b / 24; }
    else if (b < 1152) { in = W1 + 768*768; op = W1x + 768*768; R = 768; C = 768; bx = (b-576) % 24;  by = (b-576) / 24; }
    else if (b < 1440) { in = W2;           op = W2t;           R = 768; C = 384; bx = (b-1152) % 12; by = (b-1152) / 12; }
    else               { in = W3;           op = W3t;           R = 384; C = 128; bx = (b-1440) % 4;  by = (b-1440) / 4; }
    int c0 = bx * 32, r0 = by * 32;
    int tx = threadIdx.x, ty = threadIdx.y;   // 32 x 8
    #pragma unroll
    for (int k = 0; k < 4; ++k)
        t[ty + 8*k][tx] = in[(size_t)(r0 + ty + 8*k) * C + c0 + tx];
    __syncthreads();
    #pragma unroll
    for (int k = 0; k < 4; ++k)
        op[(size_t)(c0 + ty + 8*k) * R + r0 + tx] = f2bf1(t[tx][ty + 8*k]);
}

// ---------------- AB = feat @ W1x^T (+b1 on A half) : M=256, N=1536, K=768 ------
// 96 blocks of 64m x 64n; 4 waves, wave n-band = wid*16
__launch_bounds__(256, 2)
__global__ void ab_gemm_k(const float* __restrict__ F,
                          const unsigned short* __restrict__ W,
                          const float* __restrict__ b1,
                          float* __restrict__ AB) {
    __shared__ alignas(1024) unsigned short fl[2][64*72];   // 18,432 B
    __shared__ alignas(1024) unsigned short wl[2][64*64];   // 16,384 B (swizzled)
    int tid = threadIdx.x;
    int lane = tid & 63, wid = tid >> 6;   // 4 waves
    int n0 = blockIdx.x * 64, m0 = blockIdx.y * 64;
    f32x4 acc[4] = {};
    float4 rf[2][2];

    #pragma unroll
    for (int s = 0; s < 2; ++s) {          // W tile 64x64 -> 8 chunks of 1024B
        int chunk = wid*2 + s;
        int row = chunk*8 + (lane>>3);
        int cg = (lane&7) ^ (row&7);
        gload_lds16(W + (size_t)(n0 + row)*HID + cg*8, (char*)wl[0] + chunk*1024);
    }
    #pragma unroll
    for (int s = 0; s < 2; ++s) {          // F tile 64x64 f32
        int idx = tid + s*256;
        int r = idx >> 3, c8 = idx & 7;
        const float4* src = (const float4*)(F + (size_t)(m0 + r)*HID + c8*8);
        rf[s][0] = src[0]; rf[s][1] = src[1];
    }
    #pragma unroll
    for (int s = 0; s < 2; ++s) {
        int idx = tid + s*256;
        int r = idx >> 3, c8 = idx & 7;
        unsigned int us32[4] = { pack2bf(rf[s][0].x, rf[s][0].y), pack2bf(rf[s][0].z, rf[s][0].w),
                                 pack2bf(rf[s][1].x, rf[s][1].y), pack2bf(rf[s][1].z, rf[s][1].w) };
        *(ushort8_t*)(fl[0] + r*72 + c8*8) = *(ushort8_t*)us32;
    }
    __syncthreads();

    for (int t = 0; t < 12; ++t) {
        int cur = t & 1;
        if (t < 11) {
            int kk = (t+1) * 64;
            #pragma unroll
            for (int s = 0; s < 2; ++s) {
                int chunk = wid*2 + s;
                int row = chunk*8 + (lane>>3);
                int cg = (lane&7) ^ (row&7);
                gload_lds16(W + (size_t)(n0 + row)*HID + kk + cg*8, (char*)wl[cur^1] + chunk*1024);
            }
            #pragma unroll
            for (int s = 0; s < 2; ++s) {
                int idx = tid + s*256;
                int r = idx >> 3, c8 = idx & 7;
                const float4* src = (const float4*)(F + (size_t)(m0 + r)*HID + kk + c8*8);
                rf[s][0] = src[0]; rf[s][1] = src[1];
            }
        }
        __builtin_amdgcn_s_setprio(1);
        #pragma unroll
        for (int ks = 0; ks < 2; ++ks) {
            bf16x8 a[4], b;
            #pragma unroll
            for (int fm = 0; fm < 4; ++fm)
                a[fm] = *(const bf16x8*)(fl[cur] + (fm*16 + (lane&15))*72 + ks*32 + (lane>>4)*8);
            {
                int n = wid*16 + (lane&15);
                int g = ks*4 + (lane>>4);
                b = *(const bf16x8*)(wl[cur] + n*64 + ((g ^ (n&7)) * 8));
            }
            #pragma unroll
            for (int fm = 0; fm < 4; ++fm)
                acc[fm] = __builtin_amdgcn_mfma_f32_16x16x32_bf16(a[fm], b, acc[fm], 0,0,0);
        }
        __builtin_amdgcn_s_setprio(0);
        if (t < 11) {
            #pragma unroll
            for (int s = 0; s < 2; ++s) {
                int idx = tid + s*256;
                int r = idx >> 3, c8 = idx & 7;
                unsigned int us32[4] = { pack2bf(rf[s][0].x, rf[s][0].y), pack2bf(rf[s][0].z, rf[s][0].w),
                                         pack2bf(rf[s][1].x, rf[s][1].y), pack2bf(rf[s][1].z, rf[s][1].w) };
                *(ushort8_t*)(fl[cur^1] + r*72 + c8*8) = *(ushort8_t*)us32;
            }
        }
        __syncthreads();
    }
    #pragma unroll
    for (int fm = 0; fm < 4; ++fm)
        #pragma unroll
        for (int q = 0; q < 4; ++q) {
            int row = m0 + fm*16 + (lane>>4)*4 + q;
            int col = n0 + wid*16 + (lane&15);
            float bias = (col < 768) ? b1[col] : 0.0f;
            AB[(size_t)row*1536 + col] = acc[fm][q] + bias;
        }
}

// ---------------- fused pair MLP: W2/W3 B-frags global->VGPR, h1/h2 in LDS ------
// 255 blocks x 128 pairs; 1024 thr = 16 waves; phase A grid 2x8, phase B 4x4
__launch_bounds__(1024, 1)
__global__ void fused_k(const float* __restrict__ AB,            // [256][1536] f32
                        const unsigned short* __restrict__ W2t,  // [384][768] bf16
                        const float* __restrict__ b2,            // [384]
                        const unsigned short* __restrict__ W3t,  // [128][384] bf16
                        const float* __restrict__ b3,            // [128]
                        float* __restrict__ out) {               // [32640][128] f32
    __shared__ alignas(1024) char smem[100352];
    unsigned short* h1_0 = (unsigned short*)(smem);           // [128][72] buf 0
    unsigned short* h1_1 = (unsigned short*)(smem + 18432);   // [128][72] buf 1
    unsigned short* h2   = (unsigned short*)(smem);           // [128][392] phase B (reuse)

    int tid = threadIdx.x;
    int lane = tid & 63, wid = tid >> 6;   // 16 waves
    int wr = wid >> 3, wc = wid & 7;       // phase A: 2 x 8 wave grid
    int p0 = blockIdx.x * 128;

    // per-thread pair indices for my h1-gen row (8 threads per row)
    int hr = tid >> 3;                     // 0..127
    int hc = (tid & 7) * 8;                // col chunk within 64
    int p = p0 + hr;
    float sdisc = sqrtf((float)(511*511 - 8*p));
    int i_me = (int)((511.0f - sdisc) * 0.5f);
    if (i_me < 0) i_me = 0; if (i_me > 254) i_me = 254;
    while (i_me < 255 && (i_me+1)*255 - (i_me+1)*i_me/2 <= p) ++i_me;
    while (i_me > 0 && i_me*255 - i_me*(i_me-1)/2 > p) --i_me;
    int j_me = i_me + 1 + (p - (i_me*255 - i_me*(i_me-1)/2));

    const size_t abbase_i = (size_t)i_me*1536 + hc;
    const size_t abbase_j = (size_t)j_me*1536 + 768 + hc;
    const size_t w2base   = (size_t)(wc*48 + (lane&15))*768 + (lane>>4)*8;

    float4 ra0, ra1, rb0, rb1;
    bf16x8 bA[3][2], bB[3][2];
    f32x4 acc2[4][3] = {};

#define H1_LOAD(KKN) { \
    const float4* pa_ = (const float4*)(AB + abbase_i + (KKN)); \
    const float4* pb_ = (const float4*)(AB + abbase_j + (KKN)); \
    ra0 = pa_[0]; ra1 = pa_[1]; rb0 = pb_[0]; rb1 = pb_[1]; }

#define H1_PACK(H1N) { \
    unsigned int us32_[4] = { \
        pack2bf(fmaxf(ra0.x + rb0.x, 0.f), fmaxf(ra0.y + rb0.y, 0.f)), \
        pack2bf(fmaxf(ra0.z + rb0.z, 0.f), fmaxf(ra0.w + rb0.w, 0.f)), \
        pack2bf(fmaxf(ra1.x + rb1.x, 0.f), fmaxf(ra1.y + rb1.y, 0.f)), \
        pack2bf(fmaxf(ra1.z + rb1.z, 0.f), fmaxf(ra1.w + rb1.w, 0.f)) }; \
    *(ushort8_t*)((H1N) + hr*72 + hc) = *(ushort8_t*)us32_; }

#define PREFETCH_B(BP, KKN) { \
    _Pragma("unroll") for (int fn_ = 0; fn_ < 3; ++fn_) \
    _Pragma("unroll") for (int ks_ = 0; ks_ < 2; ++ks_) \
        BP[fn_][ks_] = *(const bf16x8*)(W2t + w2base + fn_*(16*768) + (KKN) + ks_*32); }

#define MFMA_A(H1C, BU) { \
    __builtin_amdgcn_s_setprio(1); \
    _Pragma("unroll") for (int ks_ = 0; ks_ < 2; ++ks_) { \
        bf16x8 a_[4]; \
        _Pragma("unroll") for (int fm_ = 0; fm_ < 4; ++fm_) \
            a_[fm_] = *(const bf16x8*)((H1C) + (wr*64 + fm_*16 + (lane&15))*72 + ks_*32 + (lane>>4)*8); \
        _Pragma("unroll") for (int fm_ = 0; fm_ < 4; ++fm_) \
        _Pragma("unroll") for (int fn_ = 0; fn_ < 3; ++fn_) \
            acc2[fm_][fn_] = __builtin_amdgcn_mfma_f32_16x16x32_bf16(a_[fm_], BU[fn_][ks_], acc2[fm_][fn_], 0,0,0); } \
    __builtin_amdgcn_s_setprio(0); }

#define BAR() { asm volatile("s_waitcnt lgkmcnt(0)" ::: "memory"); \
    __builtin_amdgcn_sched_barrier(0); __builtin_amdgcn_s_barrier(); }

    // ---- prologue: h1(0), b-frags(0)
    H1_LOAD(0);
    PREFETCH_B(bA, 0);
    H1_PACK(h1_0);
    BAR();

    // ---- phase A: 12 K-steps, explicit even/odd ping-pong
    for (int t2 = 0; t2 < 5; ++t2) {
        int kkE = (2*t2 + 1) * 64;         // next-k for even step
        int kkO = (2*t2 + 2) * 64;         // next-k for odd step
        // even step t=2*t2: use bA, read h1_0, write h1_1
        H1_LOAD(kkE); PREFETCH_B(bB, kkE); H1_PACK(h1_1); MFMA_A(h1_0, bA); BAR();
        // odd step t=2*t2+1: use bB, read h1_1, write h1_0
        H1_LOAD(kkO); PREFETCH_B(bA, kkO); H1_PACK(h1_0); MFMA_A(h1_1, bB); BAR();
    }
    {   // t=10: use bA, read h1_0, write h1_1; prefetch bB for t=11
        int kk = 11*64;
        H1_LOAD(kk); PREFETCH_B(bB, kk); H1_PACK(h1_1); MFMA_A(h1_0, bA); BAR();
    }
    {   // t=11: use bB, read h1_1; no loads
        MFMA_A(h1_1, bB); BAR();           // after this, h1 region reusable as h2
    }

    // ---- phase B prologue: w3(0) frags (issue first), then h2 writes
    int wrB = wid >> 2, wcB = wid & 3;     // 4 x 4 wave grid
    const size_t w3base = (size_t)(wcB*32 + (lane&15))*384 + (lane>>4)*8;
    bf16x8 wA[2][2], wB[2][2];
    f32x4 acc3[2][2] = {};

#define PREFETCH_W3(WP, KT) { \
    _Pragma("unroll") for (int fn_ = 0; fn_ < 2; ++fn_) \
    _Pragma("unroll") for (int ks_ = 0; ks_ < 2; ++ks_) \
        WP[fn_][ks_] = *(const bf16x8*)(W3t + w3base + fn_*(16*384) + (KT)*64 + ks_*32); }

#define MFMA_B(WU, KT) { \
    __builtin_amdgcn_s_setprio(1); \
    _Pragma("unroll") for (int ks_ = 0; ks_ < 2; ++ks_) { \
        bf16x8 a_[2]; \
        _Pragma("unroll") for (int fm_ = 0; fm_ < 2; ++fm_) \
            a_[fm_] = *(const bf16x8*)(h2 + (wrB*32 + fm_*16 + (lane&15))*392 + (KT)*64 + ks_*32 + (lane>>4)*8); \
        _Pragma("unroll") for (int fm_ = 0; fm_ < 2; ++fm_) \
        _Pragma("unroll") for (int fn_ = 0; fn_ < 2; ++fn_) \
            acc3[fm_][fn_] = __builtin_amdgcn_mfma_f32_16x16x32_bf16(a_[fm_], WU[fn_][ks_], acc3[fm_][fn_], 0,0,0); } \
    __builtin_amdgcn_s_setprio(0); }

    PREFETCH_W3(wA, 0);
    // h2 = relu(acc2 + b2) -> LDS [128][392]
    #pragma unroll
    for (int fn = 0; fn < 3; ++fn) {
        int col = wc*48 + fn*16 + (lane&15);
        float bb = b2[col];
        #pragma unroll
        for (int fm = 0; fm < 4; ++fm)
            #pragma unroll
            for (int q = 0; q < 4; ++q) {
                int row = wr*64 + fm*16 + (lane>>4)*4 + q;
                h2[row*392 + col] = f2bf1(fmaxf(acc2[fm][fn][q] + bb, 0.f));
            }
    }
    BAR();                                  // h2 visible; w3(0) still in flight

    // ---- phase B: 6 K-steps, barrier-free, fully unrolled even/odd
    PREFETCH_W3(wB, 1); MFMA_B(wA, 0);
    PREFETCH_W3(wA, 2); MFMA_B(wB, 1);
    PREFETCH_W3(wB, 3); MFMA_B(wA, 2);
    PREFETCH_W3(wA, 4); MFMA_B(wB, 3);
    PREFETCH_W3(wB, 5); MFMA_B(wA, 4);
    MFMA_B(wB, 5);

    #pragma unroll
    for (int fm = 0; fm < 2; ++fm)
        #pragma unroll
        for (int fn = 0; fn < 2; ++fn) {
            int col = wcB*32 + fn*16 + (lane&15);
            float bb = b3[col];
            #pragma unroll
            for (int q = 0; q < 4; ++q) {
                int row = p0 + wrB*32 + fm*16 + (lane>>4)*4 + q;
                out[(size_t)row*128 + col] = acc3[fm][fn][q] + bb;
            }
        }
}

extern "C" void kernel_launch(void* const* d_in, const int* in_sizes, int n_in,
                              void* d_out, int out_size, void* d_ws, size_t ws_size,
                              hipStream_t stream) {
    const float* feat = (const float*)d_in[0];  // [256][768]
    const float* W1   = (const float*)d_in[1];  // [1536][768]
    const float* b1   = (const float*)d_in[2];  // [768]
    const float* W2   = (const float*)d_in[3];  // [768][384]
    const float* b2   = (const float*)d_in[4];  // [384]
    const float* W3   = (const float*)d_in[5];  // [384][128]
    const float* b3   = (const float*)d_in[6];  // [128]
    float* out = (float*)d_out;

    char* ws = (char*)d_ws;
    unsigned short* W1x = (unsigned short*)(ws + 0);        // 1536*768*2 = 2,359,296
    unsigned short* W2t = (unsigned short*)(ws + 2359296);  // 384*768*2  =   589,824
    unsigned short* W3t = (unsigned short*)(ws + 2949120);  // 128*384*2  =    98,304
    float*          AB  = (float*)        (ws + 3047424);   // 256*1536*4 = 1,572,864

    prep_k<<<1488, dim3(32,8), 0, stream>>>(W1, W2, W3, W1x, W2t, W3t);
    ab_gemm_k<<<dim3(24,4), 256, 0, stream>>>(feat, W1x, b1, AB);
    fused_k<<<255, 1024, 0, stream>>>(AB, W2t, b2, W3t, b3, out);
}

// Round 7
// 78.118 us; speedup vs baseline: 1.0806x; 1.0806x over previous
//
#include <hip/hip_runtime.h>
#include <hip/hip_bf16.h>
#include <stdint.h>

#define HID 768

typedef short bf16x8 __attribute__((ext_vector_type(8)));
typedef unsigned short ushort8_t __attribute__((ext_vector_type(8)));
typedef float f32x4 __attribute__((ext_vector_type(4)));

// packed f32x2 -> bf16x2 (compiler emits v_cvt_pk_bf16_f32)
__device__ __forceinline__ unsigned int pack2bf(float x, float y) {
    __hip_bfloat162 h = __float22bfloat162_rn(make_float2(x, y));
    return *reinterpret_cast<unsigned int*>(&h);
}
__device__ __forceinline__ unsigned short f2bf1(float x) {
    __hip_bfloat16 h = __float2bfloat16(x);
    return *reinterpret_cast<unsigned short*>(&h);
}

// async global->LDS, 16B per lane; lds dest = wave-uniform base + lane*16
__device__ __forceinline__ void gload_lds16(const void* g, void* l) {
    __builtin_amdgcn_global_load_lds(
        (const __attribute__((address_space(1))) unsigned int*)g,
        (__attribute__((address_space(3))) unsigned int*)l, 16, 0, 0);
}

// ---------------- merged transpose+cast: 4 regions, f32 [R][C] -> bf16 [C][R] ----
__global__ void prep_k(const float* __restrict__ W1,
                       const float* __restrict__ W2,
                       const float* __restrict__ W3,
                       unsigned short* __restrict__ W1x,
                       unsigned short* __restrict__ W2t,
                       unsigned short* __restrict__ W3t) {
    __shared__ float t[32][33];
    int b = blockIdx.x;
    const float* in; unsigned short* op; int R, C, bx, by;
    if (b < 576)       { in = W1;           op = W1x;           R = 768; C = 768; bx = b % 24;        by = b / 24; }
    else if (b < 1152) { in = W1 + 768*768; op = W1x + 768*768; R = 768; C = 768; bx = (b-576) % 24;  by = (b-576) / 24; }
    else if (b < 1440) { in = W2;           op = W2t;           R = 768; C = 384; bx = (b-1152) % 12; by = (b-1152) / 12; }
    else               { in = W3;           op = W3t;           R = 384; C = 128; bx = (b-1440) % 4;  by = (b-1440) / 4; }
    int c0 = bx * 32, r0 = by * 32;
    int tx = threadIdx.x, ty = threadIdx.y;   // 32 x 8
    #pragma unroll
    for (int k = 0; k < 4; ++k)
        t[ty + 8*k][tx] = in[(size_t)(r0 + ty + 8*k) * C + c0 + tx];
    __syncthreads();
    #pragma unroll
    for (int k = 0; k < 4; ++k)
        op[(size_t)(c0 + ty + 8*k) * R + r0 + tx] = f2bf1(t[tx][ty + 8*k]);
}

// ---------------- AB = feat @ W1x^T (+b1 on A half) : M=256, N=1536, K=768 ------
// 96 blocks of 64m x 64n; 4 waves, wave n-band = wid*16
__launch_bounds__(256, 2)
__global__ void ab_gemm_k(const float* __restrict__ F,
                          const unsigned short* __restrict__ W,
                          const float* __restrict__ b1,
                          float* __restrict__ AB) {
    __shared__ alignas(1024) unsigned short fl[2][64*72];   // 18,432 B
    __shared__ alignas(1024) unsigned short wl[2][64*64];   // 16,384 B (swizzled)
    int tid = threadIdx.x;
    int lane = tid & 63, wid = tid >> 6;   // 4 waves
    int n0 = blockIdx.x * 64, m0 = blockIdx.y * 64;
    f32x4 acc[4] = {};
    float4 rf[2][2];

    #pragma unroll
    for (int s = 0; s < 2; ++s) {          // W tile 64x64 -> 8 chunks of 1024B
        int chunk = wid*2 + s;
        int row = chunk*8 + (lane>>3);
        int cg = (lane&7) ^ (row&7);
        gload_lds16(W + (size_t)(n0 + row)*HID + cg*8, (char*)wl[0] + chunk*1024);
    }
    #pragma unroll
    for (int s = 0; s < 2; ++s) {          // F tile 64x64 f32
        int idx = tid + s*256;
        int r = idx >> 3, c8 = idx & 7;
        const float4* src = (const float4*)(F + (size_t)(m0 + r)*HID + c8*8);
        rf[s][0] = src[0]; rf[s][1] = src[1];
    }
    #pragma unroll
    for (int s = 0; s < 2; ++s) {
        int idx = tid + s*256;
        int r = idx >> 3, c8 = idx & 7;
        unsigned int us32[4] = { pack2bf(rf[s][0].x, rf[s][0].y), pack2bf(rf[s][0].z, rf[s][0].w),
                                 pack2bf(rf[s][1].x, rf[s][1].y), pack2bf(rf[s][1].z, rf[s][1].w) };
        *(ushort8_t*)(fl[0] + r*72 + c8*8) = *(ushort8_t*)us32;
    }
    __syncthreads();

    for (int t = 0; t < 12; ++t) {
        int cur = t & 1;
        if (t < 11) {
            int kk = (t+1) * 64;
            #pragma unroll
            for (int s = 0; s < 2; ++s) {
                int chunk = wid*2 + s;
                int row = chunk*8 + (lane>>3);
                int cg = (lane&7) ^ (row&7);
                gload_lds16(W + (size_t)(n0 + row)*HID + kk + cg*8, (char*)wl[cur^1] + chunk*1024);
            }
            #pragma unroll
            for (int s = 0; s < 2; ++s) {
                int idx = tid + s*256;
                int r = idx >> 3, c8 = idx & 7;
                const float4* src = (const float4*)(F + (size_t)(m0 + r)*HID + kk + c8*8);
                rf[s][0] = src[0]; rf[s][1] = src[1];
            }
        }
        __builtin_amdgcn_s_setprio(1);
        #pragma unroll
        for (int ks = 0; ks < 2; ++ks) {
            bf16x8 a[4], b;
            #pragma unroll
            for (int fm = 0; fm < 4; ++fm)
                a[fm] = *(const bf16x8*)(fl[cur] + (fm*16 + (lane&15))*72 + ks*32 + (lane>>4)*8);
            {
                int n = wid*16 + (lane&15);
                int g = ks*4 + (lane>>4);
                b = *(const bf16x8*)(wl[cur] + n*64 + ((g ^ (n&7)) * 8));
            }
            #pragma unroll
            for (int fm = 0; fm < 4; ++fm)
                acc[fm] = __builtin_amdgcn_mfma_f32_16x16x32_bf16(a[fm], b, acc[fm], 0,0,0);
        }
        __builtin_amdgcn_s_setprio(0);
        if (t < 11) {
            #pragma unroll
            for (int s = 0; s < 2; ++s) {
                int idx = tid + s*256;
                int r = idx >> 3, c8 = idx & 7;
                unsigned int us32[4] = { pack2bf(rf[s][0].x, rf[s][0].y), pack2bf(rf[s][0].z, rf[s][0].w),
                                         pack2bf(rf[s][1].x, rf[s][1].y), pack2bf(rf[s][1].z, rf[s][1].w) };
                *(ushort8_t*)(fl[cur^1] + r*72 + c8*8) = *(ushort8_t*)us32;
            }
        }
        __syncthreads();
    }
    #pragma unroll
    for (int fm = 0; fm < 4; ++fm)
        #pragma unroll
        for (int q = 0; q < 4; ++q) {
            int row = m0 + fm*16 + (lane>>4)*4 + q;
            int col = n0 + wid*16 + (lane&15);
            float bias = (col < 768) ? b1[col] : 0.0f;
            AB[(size_t)row*1536 + col] = acc[fm][q] + bias;
        }
}

// ---------------- fused pair MLP: 512 thr / 8 waves (2 per SIMD, 256-reg budget)
// W2/W3 B-frags global->VGPR (dbuf); only h1/h2 route through LDS.
// phase A grid 2x4 (wave tile 64x96); phase B grid 2x4 (tile 64x32), barrier-free
__launch_bounds__(512, 2)
__global__ void fused_k(const float* __restrict__ AB,            // [256][1536] f32
                        const unsigned short* __restrict__ W2t,  // [384][768] bf16
                        const float* __restrict__ b2,            // [384]
                        const unsigned short* __restrict__ W3t,  // [128][384] bf16
                        const float* __restrict__ b3,            // [128]
                        float* __restrict__ out) {               // [32640][128] f32
    __shared__ alignas(1024) char smem[100352];
    unsigned short* h1_0 = (unsigned short*)(smem);           // [128][72] buf 0
    unsigned short* h1_1 = (unsigned short*)(smem + 18432);   // [128][72] buf 1
    unsigned short* h2   = (unsigned short*)(smem);           // [128][392] phase B (reuse)

    int tid = threadIdx.x;
    int lane = tid & 63, wid = tid >> 6;   // 8 waves
    int wr = wid >> 2, wc = wid & 3;       // phase A: 2 x 4 wave grid
    int p0 = blockIdx.x * 128;

    // per-thread pair indices for my h1-gen row (4 threads per row, 16 cols each)
    int hr = tid >> 2;                     // 0..127
    int hc = (tid & 3) * 16;               // col chunk within 64
    int p = p0 + hr;
    float sdisc = sqrtf((float)(511*511 - 8*p));
    int i_me = (int)((511.0f - sdisc) * 0.5f);
    if (i_me < 0) i_me = 0; if (i_me > 254) i_me = 254;
    while (i_me < 255 && (i_me+1)*255 - (i_me+1)*i_me/2 <= p) ++i_me;
    while (i_me > 0 && i_me*255 - i_me*(i_me-1)/2 > p) --i_me;
    int j_me = i_me + 1 + (p - (i_me*255 - i_me*(i_me-1)/2));

    const size_t abbase_i = (size_t)i_me*1536 + hc;
    const size_t abbase_j = (size_t)j_me*1536 + 768 + hc;
    const size_t w2base   = (size_t)(wc*96 + (lane&15))*768 + (lane>>4)*8;

    float4 ra0, ra1, ra2, ra3, rb0, rb1, rb2, rb3;
    bf16x8 bA[6][2], bB[6][2];
    f32x4 acc2[4][6] = {};

#define H1_LOAD(KKN) { \
    const float4* pa_ = (const float4*)(AB + abbase_i + (KKN)); \
    const float4* pb_ = (const float4*)(AB + abbase_j + (KKN)); \
    ra0 = pa_[0]; ra1 = pa_[1]; ra2 = pa_[2]; ra3 = pa_[3]; \
    rb0 = pb_[0]; rb1 = pb_[1]; rb2 = pb_[2]; rb3 = pb_[3]; }

#define H1_PACK(H1N) { \
    unsigned int us32_[8] = { \
        pack2bf(fmaxf(ra0.x + rb0.x, 0.f), fmaxf(ra0.y + rb0.y, 0.f)), \
        pack2bf(fmaxf(ra0.z + rb0.z, 0.f), fmaxf(ra0.w + rb0.w, 0.f)), \
        pack2bf(fmaxf(ra1.x + rb1.x, 0.f), fmaxf(ra1.y + rb1.y, 0.f)), \
        pack2bf(fmaxf(ra1.z + rb1.z, 0.f), fmaxf(ra1.w + rb1.w, 0.f)), \
        pack2bf(fmaxf(ra2.x + rb2.x, 0.f), fmaxf(ra2.y + rb2.y, 0.f)), \
        pack2bf(fmaxf(ra2.z + rb2.z, 0.f), fmaxf(ra2.w + rb2.w, 0.f)), \
        pack2bf(fmaxf(ra3.x + rb3.x, 0.f), fmaxf(ra3.y + rb3.y, 0.f)), \
        pack2bf(fmaxf(ra3.z + rb3.z, 0.f), fmaxf(ra3.w + rb3.w, 0.f)) }; \
    *(ushort8_t*)((H1N) + hr*72 + hc)     = *(ushort8_t*)(us32_); \
    *(ushort8_t*)((H1N) + hr*72 + hc + 8) = *(ushort8_t*)(us32_ + 4); }

#define PREFETCH_B(BP, KKN) { \
    _Pragma("unroll") for (int fn_ = 0; fn_ < 6; ++fn_) \
    _Pragma("unroll") for (int ks_ = 0; ks_ < 2; ++ks_) \
        BP[fn_][ks_] = *(const bf16x8*)(W2t + w2base + fn_*(16*768) + (KKN) + ks_*32); }

#define MFMA_A(H1C, BU) { \
    __builtin_amdgcn_s_setprio(1); \
    _Pragma("unroll") for (int ks_ = 0; ks_ < 2; ++ks_) { \
        bf16x8 a_[4]; \
        _Pragma("unroll") for (int fm_ = 0; fm_ < 4; ++fm_) \
            a_[fm_] = *(const bf16x8*)((H1C) + (wr*64 + fm_*16 + (lane&15))*72 + ks_*32 + (lane>>4)*8); \
        _Pragma("unroll") for (int fm_ = 0; fm_ < 4; ++fm_) \
        _Pragma("unroll") for (int fn_ = 0; fn_ < 6; ++fn_) \
            acc2[fm_][fn_] = __builtin_amdgcn_mfma_f32_16x16x32_bf16(a_[fm_], BU[fn_][ks_], acc2[fm_][fn_], 0,0,0); } \
    __builtin_amdgcn_s_setprio(0); }

#define BAR() { asm volatile("s_waitcnt lgkmcnt(0)" ::: "memory"); \
    __builtin_amdgcn_sched_barrier(0); __builtin_amdgcn_s_barrier(); }

    // ---- prologue: h1(0), b-frags(0)
    H1_LOAD(0);
    PREFETCH_B(bA, 0);
    H1_PACK(h1_0);
    BAR();

    // ---- phase A: 12 K-steps, explicit even/odd ping-pong
    for (int t2 = 0; t2 < 5; ++t2) {
        int kkE = (2*t2 + 1) * 64;
        int kkO = (2*t2 + 2) * 64;
        H1_LOAD(kkE); PREFETCH_B(bB, kkE); H1_PACK(h1_1); MFMA_A(h1_0, bA); BAR();
        H1_LOAD(kkO); PREFETCH_B(bA, kkO); H1_PACK(h1_0); MFMA_A(h1_1, bB); BAR();
    }
    {   // t=10
        int kk = 11*64;
        H1_LOAD(kk); PREFETCH_B(bB, kk); H1_PACK(h1_1); MFMA_A(h1_0, bA); BAR();
    }
    {   // t=11
        MFMA_A(h1_1, bB); BAR();           // after this, h1 region reusable as h2
    }

    // ---- phase B prologue: w3(0) frags first, then h2 writes
    int wrB = wid >> 2, wcB = wid & 3;     // 2 x 4 wave grid, tile 64 x 32
    const size_t w3base = (size_t)(wcB*32 + (lane&15))*384 + (lane>>4)*8;
    bf16x8 wA[2][2], wB[2][2];
    f32x4 acc3[4][2] = {};

#define PREFETCH_W3(WP, KT) { \
    _Pragma("unroll") for (int fn_ = 0; fn_ < 2; ++fn_) \
    _Pragma("unroll") for (int ks_ = 0; ks_ < 2; ++ks_) \
        WP[fn_][ks_] = *(const bf16x8*)(W3t + w3base + fn_*(16*384) + (KT)*64 + ks_*32); }

#define MFMA_B(WU, KT) { \
    __builtin_amdgcn_s_setprio(1); \
    _Pragma("unroll") for (int ks_ = 0; ks_ < 2; ++ks_) { \
        bf16x8 a_[4]; \
        _Pragma("unroll") for (int fm_ = 0; fm_ < 4; ++fm_) \
            a_[fm_] = *(const bf16x8*)(h2 + (wrB*64 + fm_*16 + (lane&15))*392 + (KT)*64 + ks_*32 + (lane>>4)*8); \
        _Pragma("unroll") for (int fm_ = 0; fm_ < 4; ++fm_) \
        _Pragma("unroll") for (int fn_ = 0; fn_ < 2; ++fn_) \
            acc3[fm_][fn_] = __builtin_amdgcn_mfma_f32_16x16x32_bf16(a_[fm_], WU[fn_][ks_], acc3[fm_][fn_], 0,0,0); } \
    __builtin_amdgcn_s_setprio(0); }

    PREFETCH_W3(wA, 0);
    // h2 = relu(acc2 + b2) -> LDS [128][392]
    #pragma unroll
    for (int fn = 0; fn < 6; ++fn) {
        int col = wc*96 + fn*16 + (lane&15);
        float bb = b2[col];
        #pragma unroll
        for (int fm = 0; fm < 4; ++fm)
            #pragma unroll
            for (int q = 0; q < 4; ++q) {
                int row = wr*64 + fm*16 + (lane>>4)*4 + q;
                h2[row*392 + col] = f2bf1(fmaxf(acc2[fm][fn][q] + bb, 0.f));
            }
    }
    BAR();                                  // h2 visible; w3(0) still in flight

    // ---- phase B: 6 K-steps, barrier-free, fully unrolled even/odd
    PREFETCH_W3(wB, 1); MFMA_B(wA, 0);
    PREFETCH_W3(wA, 2); MFMA_B(wB, 1);
    PREFETCH_W3(wB, 3); MFMA_B(wA, 2);
    PREFETCH_W3(wA, 4); MFMA_B(wB, 3);
    PREFETCH_W3(wB, 5); MFMA_B(wA, 4);
    MFMA_B(wB, 5);

    #pragma unroll
    for (int fm = 0; fm < 4; ++fm)
        #pragma unroll
        for (int fn = 0; fn < 2; ++fn) {
            int col = wcB*32 + fn*16 + (lane&15);
            float bb = b3[col];
            #pragma unroll
            for (int q = 0; q < 4; ++q) {
                int row = p0 + wrB*64 + fm*16 + (lane>>4)*4 + q;
                out[(size_t)row*128 + col] = acc3[fm][fn][q] + bb;
            }
        }
}

extern "C" void kernel_launch(void* const* d_in, const int* in_sizes, int n_in,
                              void* d_out, int out_size, void* d_ws, size_t ws_size,
                              hipStream_t stream) {
    const float* feat = (const float*)d_in[0];  // [256][768]
    const float* W1   = (const float*)d_in[1];  // [1536][768]
    const float* b1   = (const float*)d_in[2];  // [768]
    const float* W2   = (const float*)d_in[3];  // [768][384]
    const float* b2   = (const float*)d_in[4];  // [384]
    const float* W3   = (const float*)d_in[5];  // [384][128]
    const float* b3   = (const float*)d_in[6];  // [128]
    float* out = (float*)d_out;

    char* ws = (char*)d_ws;
    unsigned short* W1x = (unsigned short*)(ws + 0);        // 1536*768*2 = 2,359,296
    unsigned short* W2t = (unsigned short*)(ws + 2359296);  // 384*768*2  =   589,824
    unsigned short* W3t = (unsigned short*)(ws + 2949120);  // 128*384*2  =    98,304
    float*          AB  = (float*)        (ws + 3047424);   // 256*1536*4 = 1,572,864

    prep_k<<<1488, dim3(32,8), 0, stream>>>(W1, W2, W3, W1x, W2t, W3t);
    ab_gemm_k<<<dim3(24,4), 256, 0, stream>>>(feat, W1x, b1, AB);
    fused_k<<<255, 512, 0, stream>>>(AB, W2t, b2, W3t, b3, out);
}